// Round 10
// baseline (243.533 us; speedup 1.0000x reference)
//
#include <hip/hip_runtime.h>
#include <hip/hip_bf16.h>
#include <hip/hip_cooperative_groups.h>

namespace cg = cooperative_groups;

#define NSEG 50000
#define GRID 512
#define CH 8

typedef __attribute__((ext_vector_type(4))) float f32x4;
typedef __attribute__((ext_vector_type(8))) short s16x8;

static __device__ __forceinline__ unsigned short f2bf(float f) {
  unsigned int u = __float_as_uint(f);
  u += 0x7fffu + ((u >> 16) & 1u);   // round-to-nearest-even
  return (unsigned short)(u >> 16);
}

static __device__ __forceinline__ s16x8 pack_bf16x8(const float* p) {
  float4 p0 = *(const float4*)(p);
  float4 p1 = *(const float4*)(p + 4);
  s16x8 v;
  v[0] = (short)f2bf(p0.x); v[1] = (short)f2bf(p0.y);
  v[2] = (short)f2bf(p0.z); v[3] = (short)f2bf(p0.w);
  v[4] = (short)f2bf(p1.x); v[5] = (short)f2bf(p1.y);
  v[6] = (short)f2bf(p1.z); v[7] = (short)f2bf(p1.w);
  return v;
}

// ---------------------------------------------------------------------------
// prep: Wb = bf16(W); wb_cat = a-folded 16x128 bf16; denom = 0.
// ---------------------------------------------------------------------------
__global__ __launch_bounds__(256) void prep_kernel(
    const float* __restrict__ W, const float* __restrict__ a_src,
    const float* __restrict__ a_tgt, unsigned short* __restrict__ Wb,
    unsigned short* __restrict__ wb_cat, float* __restrict__ denom) {
  int t = blockIdx.x * 256 + threadIdx.x;
  if (t < 32768) Wb[t] = f2bf(W[t]);
  if (t < 2048) {
    int row = t >> 7, k = t & 127;
    int h = row & 7;
    const float* a = (row < 8) ? a_src : a_tgt;
    float acc = 0.f;
    for (int f = 0; f < 32; ++f) acc += W[(h * 32 + f) * 128 + k] * a[h * 32 + f];
    wb_cat[t] = f2bf(acc);
  }
  if (t < NSEG * 8) denom[t] = 0.f;
}

// ---------------------------------------------------------------------------
// fused: phase1 scores (retain msg_tgt fragments in VGPR, ex in LDS),
// grid.sync, phase2 projection+epilogue. denom read with AGENT-scope atomic
// loads (cross-XCD L2 coherence — plain loads raced in R9).
// ---------------------------------------------------------------------------
__global__ __launch_bounds__(256, 2) void fused_kernel(
    const float* __restrict__ msg, const int* __restrict__ index,
    const unsigned short* __restrict__ Wb,
    const unsigned short* __restrict__ wb_cat, float* __restrict__ denom,
    float* __restrict__ out, int n) {
  __shared__ unsigned short kv[4][4][64][8];  // 16 KB fragment exchange
  __shared__ float exl[CH][64][8];            // 16 KB ex (LDS-resident)
  __shared__ float att_lds[64][9];
  __shared__ float stg[2][16][260];           // 33 KB store staging

  int tid = threadIdx.x;
  int w = tid >> 6, l = tid & 63;
  int lcol = l & 15, kgrp = l >> 4;

  s16x8 bfrag[CH][4];  // retained msg_tgt fragments (128 VGPR)

  // ---------------- phase 1: scores ----------------
  {
    s16x8 cfrag[4];
#pragma unroll
    for (int kk = 0; kk < 4; ++kk)
      cfrag[kk] = *(const s16x8*)(wb_cat + lcol * 128 + kk * 32 + kgrp * 8);

#pragma unroll
    for (int c = 0; c < CH; ++c) {
      int ge = (blockIdx.x * CH + c) * 64 + w * 16 + lcol;
      int ga = ge < n ? ge : n - 1;
      const float* rs = msg + (size_t)ga * 128;
      const float* rt = msg + ((size_t)ga + (size_t)n) * 128;

      f32x4 ds = {0.f, 0.f, 0.f, 0.f};
      f32x4 dt = {0.f, 0.f, 0.f, 0.f};
#pragma unroll
      for (int kk = 0; kk < 4; ++kk) {
        int k0 = kk * 32 + kgrp * 8;
        s16x8 bs = pack_bf16x8(rs + k0);
        ds = __builtin_amdgcn_mfma_f32_16x16x32_bf16(cfrag[kk], bs, ds, 0, 0, 0);
        s16x8 bt = pack_bf16x8(rt + k0);
        bfrag[c][kk] = bt;
        dt = __builtin_amdgcn_mfma_f32_16x16x32_bf16(cfrag[kk], bt, dt, 0, 0, 0);
      }

      f32x4 evv;
#pragma unroll
      for (int r = 0; r < 4; ++r) {
        float tv = __shfl_xor(dt[r], 32);  // bring dt row h+8
        float s = ds[r] + tv;
        s = s > 0.f ? s : 0.2f * s;        // leaky_relu, NEG_SLOPE=0.2
        evv[r] = __expf(s);
      }
      if (kgrp < 2) {
#pragma unroll
        for (int r = 0; r < 4; ++r) exl[c][w * 16 + lcol][kgrp * 4 + r] = evv[r];
        if (ge < n) {
          int seg = index[ge];
#pragma unroll
          for (int r = 0; r < 4; ++r)
            atomicAdd(&denom[seg * 8 + kgrp * 4 + r], evv[r]);
        }
      }
    }
  }

  cg::this_grid().sync();

  // ---------------- phase 2: projection + epilogue ----------------
  s16x8 afrag[4][4];
#pragma unroll
  for (int ct = 0; ct < 4; ++ct) {
    int feat = w * 64 + ct * 16 + lcol;
#pragma unroll
    for (int kk = 0; kk < 4; ++kk)
      afrag[ct][kk] = *(const s16x8*)(Wb + (size_t)feat * 128 + kk * 32 + kgrp * 8);
  }

#pragma unroll
  for (int c = 0; c < CH; ++c) {
    int ebase = (blockIdx.x * CH + c) * 64;

#pragma unroll
    for (int kk = 0; kk < 4; ++kk)
      *(s16x8*)&kv[w][kk][l][0] = bfrag[c][kk];

    for (int i = tid; i < 512; i += 256) {
      int r = i >> 3, h = i & 7;
      int ge2 = ebase + r;
      float a = 0.f;
      if (ge2 < n) {
        int seg = index[ge2];
        float dv = __hip_atomic_load(&denom[seg * 8 + h], __ATOMIC_RELAXED,
                                     __HIP_MEMORY_SCOPE_AGENT);
        a = exl[c][r][h] / (dv + 1e-16f);
      }
      att_lds[r][h] = a;
    }
    asm volatile("s_waitcnt lgkmcnt(0)" ::: "memory");
    __builtin_amdgcn_s_barrier();

#pragma unroll
    for (int t = 0; t < 4; ++t) {
      s16x8 bf[4];
#pragma unroll
      for (int kk = 0; kk < 4; ++kk) bf[kk] = *(const s16x8*)&kv[t][kk][l][0];

#pragma unroll
      for (int ct = 0; ct < 4; ++ct) {
        f32x4 acc = {0.f, 0.f, 0.f, 0.f};
#pragma unroll
        for (int kk = 0; kk < 4; ++kk)
          acc = __builtin_amdgcn_mfma_f32_16x16x32_bf16(afrag[ct][kk], bf[kk], acc, 0, 0, 0);
        int f0 = w * 64 + ct * 16 + kgrp * 4;
        float a = att_lds[t * 16 + lcol][f0 >> 5];
        *(f32x4*)&stg[0][lcol][f0] = acc * a;
        *(f32x4*)&stg[1][lcol][f0] = acc;
      }
      asm volatile("s_waitcnt lgkmcnt(0)" ::: "memory");
      __builtin_amdgcn_s_barrier();

#pragma unroll
      for (int rnd = 0; rnd < 4; ++rnd) {
        int er = rnd * 4 + w;
        int ge2 = ebase + t * 16 + er;
        if (ge2 < n) {
          f32x4 v0 = *(const f32x4*)(&stg[0][er][0] + l * 4);
          __builtin_nontemporal_store(v0, (f32x4*)(out + (size_t)ge2 * 256 + l * 4));
          f32x4 v1 = *(const f32x4*)(&stg[1][er][0] + l * 4);
          __builtin_nontemporal_store(
              v1, (f32x4*)(out + ((size_t)ge2 + (size_t)n) * 256 + l * 4));
        }
      }
      asm volatile("s_waitcnt lgkmcnt(0)" ::: "memory");
      __builtin_amdgcn_s_barrier();
    }
  }
}

// ---------------------------------------------------------------------------
// Fallback pair (proven R8) — used if the cooperative launch is rejected.
// ---------------------------------------------------------------------------
__global__ __launch_bounds__(256) void score_kernel(
    const float* __restrict__ msg, const int* __restrict__ index,
    const unsigned short* __restrict__ wb_cat, float* __restrict__ ex,
    float* __restrict__ denom, int n) {
  int tid = threadIdx.x;
  int w = tid >> 6, l = tid & 63;
  int lcol = l & 15, kgrp = l >> 4;
  int ge = blockIdx.x * 64 + w * 16 + lcol;
  int ga = ge < n ? ge : n - 1;
  const float* rs = msg + (size_t)ga * 128;
  const float* rt = msg + ((size_t)ga + (size_t)n) * 128;

  s16x8 afrag[4];
#pragma unroll
  for (int kk = 0; kk < 4; ++kk)
    afrag[kk] = *(const s16x8*)(wb_cat + lcol * 128 + kk * 32 + kgrp * 8);

  f32x4 ds = {0.f, 0.f, 0.f, 0.f};
  f32x4 dt = {0.f, 0.f, 0.f, 0.f};
#pragma unroll
  for (int kk = 0; kk < 4; ++kk) {
    int k0 = kk * 32 + kgrp * 8;
    s16x8 bs = pack_bf16x8(rs + k0);
    ds = __builtin_amdgcn_mfma_f32_16x16x32_bf16(afrag[kk], bs, ds, 0, 0, 0);
    s16x8 bt = pack_bf16x8(rt + k0);
    dt = __builtin_amdgcn_mfma_f32_16x16x32_bf16(afrag[kk], bt, dt, 0, 0, 0);
  }

  f32x4 evv;
#pragma unroll
  for (int r = 0; r < 4; ++r) {
    float tv = __shfl_xor(dt[r], 32);
    float s = ds[r] + tv;
    s = s > 0.f ? s : 0.2f * s;
    evv[r] = __expf(s);
  }
  if (kgrp < 2 && ge < n) {
    int seg = index[ge];
#pragma unroll
    for (int r = 0; r < 4; ++r) atomicAdd(&denom[seg * 8 + kgrp * 4 + r], evv[r]);
    *(f32x4*)(ex + (size_t)ge * 8 + kgrp * 4) = evv;
  }
}

__global__ __launch_bounds__(256) void gemm_kernel(
    const float* __restrict__ msg, const int* __restrict__ index,
    const unsigned short* __restrict__ Wb, const float* __restrict__ ex,
    const float* __restrict__ denom, float* __restrict__ out, int n) {
  __shared__ float att_lds[64][9];
  __shared__ float stg[2][16][260];
  int tid = threadIdx.x;
  int mbase = blockIdx.x * 64;

  for (int i = tid; i < 512; i += 256) {
    int r = i >> 3, h = i & 7;
    int ge = mbase + r;
    float a = 0.f;
    if (ge < n) {
      int seg = index[ge];
      a = ex[(size_t)ge * 8 + h] / (denom[seg * 8 + h] + 1e-16f);
    }
    att_lds[r][h] = a;
  }
  __syncthreads();

  int w = tid >> 6, l = tid & 63;
  int lcol = l & 15, kgrp = l >> 4;

  s16x8 afrag[4][4];
#pragma unroll
  for (int ct = 0; ct < 4; ++ct) {
    int feat = w * 64 + ct * 16 + lcol;
#pragma unroll
    for (int kk = 0; kk < 4; ++kk)
      afrag[ct][kk] = *(const s16x8*)(Wb + (size_t)feat * 128 + kk * 32 + kgrp * 8);
  }

  for (int t = 0; t < 4; ++t) {
    int grow = mbase + t * 16 + lcol;
    int ga = grow < n ? grow : n - 1;
    const float* brow = msg + ((size_t)ga + (size_t)n) * 128;

    s16x8 bfrag[4];
#pragma unroll
    for (int kk = 0; kk < 4; ++kk) bfrag[kk] = pack_bf16x8(brow + kk * 32 + kgrp * 8);

#pragma unroll
    for (int ct = 0; ct < 4; ++ct) {
      f32x4 acc = {0.f, 0.f, 0.f, 0.f};
#pragma unroll
      for (int kk = 0; kk < 4; ++kk)
        acc = __builtin_amdgcn_mfma_f32_16x16x32_bf16(afrag[ct][kk], bfrag[kk], acc, 0, 0, 0);
      int f0 = w * 64 + ct * 16 + kgrp * 4;
      float a = att_lds[t * 16 + lcol][f0 >> 5];
      *(f32x4*)&stg[0][lcol][f0] = acc * a;
      *(f32x4*)&stg[1][lcol][f0] = acc;
    }
    asm volatile("s_waitcnt lgkmcnt(0)" ::: "memory");
    __builtin_amdgcn_s_barrier();

#pragma unroll
    for (int rnd = 0; rnd < 4; ++rnd) {
      int er = rnd * 4 + w;
      int ge = mbase + t * 16 + er;
      if (ge < n) {
        f32x4 v0 = *(const f32x4*)(&stg[0][er][0] + l * 4);
        __builtin_nontemporal_store(v0, (f32x4*)(out + (size_t)ge * 256 + l * 4));
        f32x4 v1 = *(const f32x4*)(&stg[1][er][0] + l * 4);
        __builtin_nontemporal_store(v1, (f32x4*)(out + ((size_t)ge + (size_t)n) * 256 + l * 4));
      }
    }
    asm volatile("s_waitcnt lgkmcnt(0)" ::: "memory");
    __builtin_amdgcn_s_barrier();
  }
}

// ---------------------------------------------------------------------------
extern "C" void kernel_launch(void* const* d_in, const int* in_sizes, int n_in,
                              void* d_out, int out_size, void* d_ws, size_t ws_size,
                              hipStream_t stream) {
  const float* messages = (const float*)d_in[0];
  const float* W        = (const float*)d_in[1];
  const float* a_src    = (const float*)d_in[2];
  const float* a_tgt    = (const float*)d_in[3];
  const int*   index    = (const int*)d_in[4];
  int n = in_sizes[4];  // n_edges = 250000

  char* ws = (char*)d_ws;
  unsigned short* Wb     = (unsigned short*)(ws);             // 64 KB
  unsigned short* wb_cat = (unsigned short*)(ws + 65536);     // 4 KB
  float* denom           = (float*)(ws + 69632);              // 1.6 MB
  float* ex              = (float*)(ws + 69632 + 1600000);    // 8 MB (fallback)
  float* out = (float*)d_out;

  prep_kernel<<<(NSEG * 8 + 255) / 256, 256, 0, stream>>>(W, a_src, a_tgt, Wb,
                                                          wb_cat, denom);

  void* args[] = {(void*)&messages, (void*)&index, (void*)&Wb, (void*)&wb_cat,
                  (void*)&denom, (void*)&out, (void*)&n};
  hipError_t st = hipLaunchCooperativeKernel((void*)fused_kernel, dim3(GRID),
                                             dim3(256), args, 0, stream);
  if (st != hipSuccess) {
    int nblk = (n + 63) / 64;
    score_kernel<<<nblk, 256, 0, stream>>>(messages, index, wb_cat, ex, denom, n);
    gemm_kernel<<<nblk, 256, 0, stream>>>(messages, index, Wb, ex, denom, out, n);
  }
}